// Round 16
// baseline (380.996 us; speedup 1.0000x reference)
//
#include <hip/hip_runtime.h>

#define THREADS 256
#define SCAN_BLK 1024
#define NR 8            // node ranges (counting sort + hist)
#define NC 32           // edge chunks
#define RSTRIDE 12544   // padded per-range node stride (>= ceil(100000/8))

typedef __attribute__((ext_vector_type(8))) _Float16 half8;
typedef __attribute__((ext_vector_type(4))) float floatx4;

__device__ __forceinline__ ushort f2h(float f) {
    union { _Float16 h; ushort s; } v;
    v.h = (_Float16)f;               // v_cvt_f16_f32, RNE
    return v.s;
}
__device__ __forceinline__ float h_lo(uint u) {
    union { ushort s; _Float16 h; } v; v.s = (ushort)(u & 0xFFFFu); return (float)v.h;
}
__device__ __forceinline__ float h_hi(uint u) {
    union { ushort s; _Float16 h; } v; v.s = (ushort)(u >> 16); return (float)v.h;
}

__device__ __forceinline__ void wpack_one(const float* __restrict__ W, ushort* __restrict__ Wpk,
                                          int OUT, int t) {
    int lane = t & 63, kk = (t >> 6) & 3, ct = t >> 8;
    int col = ct * 16 + (lane & 15);
    int k0 = kk * 32 + (lane >> 4) * 8;
    #pragma unroll
    for (int j = 0; j < 8; ++j)
        Wpk[t * 8 + j] = f2h(W[(size_t)(k0 + j) * OUT + col]);
}

// ====== FUSED: src histogram (blocks [0,256)) + dst histogram -> PC ([256,512))
//        + W fragment pre-pack ([512,532)) ======
__global__ __launch_bounds__(256) void hist_phaseA(const int* __restrict__ src,
                                                   const int* __restrict__ dst,
                                                   int* __restrict__ cnt_out,
                                                   ushort* __restrict__ PC,
                                                   const float* __restrict__ W1,
                                                   const float* __restrict__ W2,
                                                   const float* __restrict__ W3,
                                                   ushort* __restrict__ Wpk1,
                                                   ushort* __restrict__ Wpk2,
                                                   ushort* __restrict__ Wpk3,
                                                   int n, int E) {
    __shared__ uint cnt[RSTRIDE];
    const int Rsz = (n + NR - 1) / NR;
    const int per = (E + NC - 1) / NC;

    if (blockIdx.x < NR * NC) {
        // ---- role A: src out-degree histogram ----
        const int range = blockIdx.x % NR;
        const int chunk = blockIdx.x / NR;
        const int lo = range * Rsz;
        const int R  = min(n - lo, Rsz);
        if (R <= 0) return;
        for (int i = threadIdx.x; i < R; i += THREADS) cnt[i] = 0;
        __syncthreads();
        const int c0 = chunk * per;
        const int c1 = min(E, c0 + per);
        int i = c0 + threadIdx.x * 4;
        for (; i + 4 <= c1; i += THREADS * 4) {
            int4 v = *(const int4*)(src + i);
            if ((unsigned)(v.x - lo) < (unsigned)R) atomicAdd(&cnt[v.x - lo], 1u);
            if ((unsigned)(v.y - lo) < (unsigned)R) atomicAdd(&cnt[v.y - lo], 1u);
            if ((unsigned)(v.z - lo) < (unsigned)R) atomicAdd(&cnt[v.z - lo], 1u);
            if ((unsigned)(v.w - lo) < (unsigned)R) atomicAdd(&cnt[v.w - lo], 1u);
        }
        if (i < c1) {
            for (int e = i; e < c1 && e < i + 4; ++e) {
                int s = src[e];
                if ((unsigned)(s - lo) < (unsigned)R) atomicAdd(&cnt[s - lo], 1u);
            }
        }
        __syncthreads();
        for (int k = threadIdx.x; k < R; k += THREADS) {
            uint c = cnt[k];
            if (c) atomicAdd(&cnt_out[lo + k], (int)c);
        }
    } else if (blockIdx.x < 2 * NR * NC) {
        // ---- role B: dst histogram, packed 2 nodes/uint -> PC ----
        const int b2 = blockIdx.x - NR * NC;
        const int range = b2 % NR;
        const int chunk = b2 / NR;
        const int lo = range * Rsz;
        const int R  = min(n - lo, Rsz);
        if (R <= 0) return;
        const int Rp = (R + 2) >> 1;
        for (int i = threadIdx.x; i < Rp; i += THREADS) cnt[i] = 0;
        __syncthreads();
        const int c0 = chunk * per;
        const int c1 = min(E, c0 + per);
        int i = c0 + threadIdx.x * 4;
        for (; i + 4 <= c1; i += THREADS * 4) {
            int4 v = *(const int4*)(dst + i);
            int kx = v.x - lo, ky = v.y - lo, kz = v.z - lo, kw = v.w - lo;
            if ((unsigned)kx < (unsigned)R) atomicAdd(&cnt[kx >> 1], (kx & 1) ? 65536u : 1u);
            if ((unsigned)ky < (unsigned)R) atomicAdd(&cnt[ky >> 1], (ky & 1) ? 65536u : 1u);
            if ((unsigned)kz < (unsigned)R) atomicAdd(&cnt[kz >> 1], (kz & 1) ? 65536u : 1u);
            if ((unsigned)kw < (unsigned)R) atomicAdd(&cnt[kw >> 1], (kw & 1) ? 65536u : 1u);
        }
        if (i < c1) {
            for (int e = i; e < c1 && e < i + 4; ++e) {
                int k = dst[e] - lo;
                if ((unsigned)k < (unsigned)R) atomicAdd(&cnt[k >> 1], (k & 1) ? 65536u : 1u);
            }
        }
        __syncthreads();
        ushort* pc = PC + (size_t)(range * NC + chunk) * RSTRIDE;
        for (int k = threadIdx.x; k < R; k += THREADS) {
            uint c = cnt[k >> 1];
            pc[k] = (ushort)((k & 1) ? (c >> 16) : (c & 0xFFFFu));
        }
    } else {
        // ---- role C: W fragment pre-pack ----
        int t2 = (blockIdx.x - 2 * NR * NC) * THREADS + threadIdx.x;
        if (t2 < 2048)      wpack_one(W1, Wpk1, 128, t2);
        else if (t2 < 4096) wpack_one(W2, Wpk2, 128, t2 - 2048);
        else if (t2 < 5120) wpack_one(W3, Wpk3, 64,  t2 - 4096);
    }
}

// ====== scan phase1 (+ fused colsum): cnt_in[node] = sum_c PC; block sums ======
__global__ void scan_phase1(const ushort* __restrict__ PC, int* __restrict__ cnt_in,
                            int* __restrict__ blk_sums, int n) {
    int base = blockIdx.x * SCAN_BLK;
    int t = threadIdx.x;
    const int Rsz = (n + NR - 1) / NR;
    int sum = 0;
    for (int i = t; i < SCAN_BLK; i += THREADS) {
        int idx = base + i;
        if (idx < n) {
            int r = idx / Rsz, k = idx - r * Rsz;
            int v = 0;
            #pragma unroll 4
            for (int c = 0; c < NC; ++c)
                v += PC[(size_t)(r * NC + c) * RSTRIDE + k];
            cnt_in[idx] = v;
            sum += v;
        }
    }
    __shared__ int wsum[4];
    for (int off = 32; off > 0; off >>= 1) sum += __shfl_down(sum, off);
    if ((t & 63) == 0) wsum[t >> 6] = sum;
    __syncthreads();
    if (t == 0) blk_sums[blockIdx.x] = wsum[0] + wsum[1] + wsum[2] + wsum[3];
}

__global__ void scan_phase2(int* __restrict__ blk_sums, int nb) {
    __shared__ int s[1024];
    int t = threadIdx.x;
    s[t] = (t < nb) ? blk_sums[t] : 0;
    __syncthreads();
    for (int off = 1; off < 1024; off <<= 1) {
        int v = s[t];
        if (t >= off) v += s[t - off];
        __syncthreads();
        s[t] = v;
        __syncthreads();
    }
    if (t < nb) blk_sums[t] = (t == 0) ? 0 : s[t - 1];
}

// ====== scan phase3 (+ fused mkbase): row_off, norms, and Bbase rows ======
__global__ void scan_phase3(const int* __restrict__ cnt, const int* __restrict__ cnt_out,
                            const int* __restrict__ blk_sums, const ushort* __restrict__ PC,
                            int* __restrict__ row_off, float* __restrict__ norm_in,
                            float* __restrict__ norm_out, int* __restrict__ Bbase,
                            int n, int E) {
    __shared__ int ts[THREADS];
    int b = blockIdx.x, t = threadIdx.x;
    int base = b * SCAN_BLK + t * 4;
    const int Rsz = (n + NR - 1) / NR;
    int local[4], val[4]; int s = 0;
    #pragma unroll
    for (int k = 0; k < 4; ++k) {
        local[k] = s;
        int idx = base + k;
        int v = (idx < n) ? cnt[idx] : 0;
        val[k] = v;
        s += v;
    }
    ts[t] = s;
    __syncthreads();
    for (int off = 1; off < THREADS; off <<= 1) {
        int v = ts[t];
        if (t >= off) v += ts[t - off];
        __syncthreads();
        ts[t] = v;
        __syncthreads();
    }
    int excl = (t == 0) ? 0 : ts[t - 1];
    int boff = blk_sums[b];
    #pragma unroll
    for (int k = 0; k < 4; ++k) {
        int idx = base + k;
        if (idx < n) {
            int ro = boff + excl + local[k];
            row_off[idx] = ro;
            norm_in[idx]  = rsqrtf((float)max(val[k], 1));
            norm_out[idx] = rsqrtf((float)max(cnt_out[idx], 1));
            // fused mkbase: running prefix across chunks
            int r = idx / Rsz, kk = idx - r * Rsz;
            int bacc = ro;
            for (int c = 0; c < NC; ++c) {
                size_t pidx = (size_t)(r * NC + c) * RSTRIDE + kk;
                Bbase[pidx] = bacc;
                bacc += PC[pidx];
            }
        }
    }
    if (b == 0 && t == 0) row_off[n] = E;
}

// ====== counting-sort phase C: LDS cursors, scatter csr_src (no global atomics) ======
__global__ __launch_bounds__(256) void csr_phaseC(const int* __restrict__ src,
                                                  const int* __restrict__ dst,
                                                  const int* __restrict__ B,
                                                  int* __restrict__ csr_src, int n, int E) {
    __shared__ int cur[RSTRIDE];
    const int range = blockIdx.x % NR;
    const int chunk = blockIdx.x / NR;
    const int Rsz = (n + NR - 1) / NR;
    const int lo  = range * Rsz;
    const int R   = min(n - lo, Rsz);
    if (R <= 0) return;
    const int* b = B + (size_t)(range * NC + chunk) * RSTRIDE;
    for (int i = threadIdx.x; i < R; i += THREADS) cur[i] = b[i];
    __syncthreads();
    const int per = (E + NC - 1) / NC;
    const int c0 = chunk * per;
    const int c1 = min(E, c0 + per);
    int i = c0 + threadIdx.x * 4;
    for (; i + 4 <= c1; i += THREADS * 4) {
        int4 d = *(const int4*)(dst + i);
        int4 s = *(const int4*)(src + i);
        int kx = d.x - lo, ky = d.y - lo, kz = d.z - lo, kw = d.w - lo;
        if ((unsigned)kx < (unsigned)R) csr_src[atomicAdd(&cur[kx], 1)] = s.x;
        if ((unsigned)ky < (unsigned)R) csr_src[atomicAdd(&cur[ky], 1)] = s.y;
        if ((unsigned)kz < (unsigned)R) csr_src[atomicAdd(&cur[kz], 1)] = s.z;
        if ((unsigned)kw < (unsigned)R) csr_src[atomicAdd(&cur[kw], 1)] = s.w;
    }
    if (i < c1) {
        for (int e = i; e < c1 && e < i + 4; ++e) {
            int k = dst[e] - lo;
            if ((unsigned)k < (unsigned)R) csr_src[atomicAdd(&cur[k], 1)] = src[e];
        }
    }
}

// ====== MFMA GEMM (layer 1): h = fp16((x*norm) @ W), 64 nodes/block ======
template<int OUT>
__global__ __launch_bounds__(256) void mfma_gemm(const float* __restrict__ x,
                                                 const ushort* __restrict__ Wpk,
                                                 const float* __restrict__ norm,
                                                 ushort* __restrict__ h, int n) {
    __shared__ ushort xs[64 * 136];
    const int t = threadIdx.x;
    const int row0 = blockIdx.x * 64;

    #pragma unroll
    for (int i = 0; i < 8; ++i) {
        int e = (i * 256 + t) * 4;
        int row = e >> 7, col = e & 127;
        int gr = min(row0 + row, n - 1);
        float nf = norm[gr];
        float4 v = *(const float4*)(x + (size_t)gr * 128 + col);
        ushort4 p;
        p.x = f2h(v.x * nf); p.y = f2h(v.y * nf);
        p.z = f2h(v.z * nf); p.w = f2h(v.w * nf);
        *(ushort4*)(&xs[row * 136 + col]) = p;
    }
    __syncthreads();

    const int wave = t >> 6, lane = t & 63;
    const int r = lane & 15, g = lane >> 4;
    const int nrow0 = row0 + wave * 16;

    half8 a[4];
    #pragma unroll
    for (int kk = 0; kk < 4; ++kk)
        a[kk] = *(const half8*)(&xs[(wave * 16 + r) * 136 + kk * 32 + g * 8]);

    const half8* wp = (const half8*)Wpk;
    #pragma unroll
    for (int ct = 0; ct < OUT / 16; ++ct) {
        floatx4 acc = {0.f, 0.f, 0.f, 0.f};
        #pragma unroll
        for (int kk = 0; kk < 4; ++kk) {
            half8 b = wp[(ct * 4 + kk) * 64 + lane];
            acc = __builtin_amdgcn_mfma_f32_16x16x32_f16(a[kk], b, acc, 0, 0, 0);
        }
        int col = ct * 16 + r;
        #pragma unroll
        for (int rr = 0; rr < 4; ++rr) {
            int grow = nrow0 + g * 4 + rr;
            if (grow < n) h[(size_t)grow * OUT + col] = f2h(acc[rr]);
        }
    }
}

// ====== FUSED: agg (128-wide fp16, unroll-8) + finalize + next-layer GEMM ======
template<int OUTN>
__global__ __launch_bounds__(256) void fused_agg_gemm(const ushort* __restrict__ h,
                                                      const int* __restrict__ row_off,
                                                      const int* __restrict__ csr_src,
                                                      const float* __restrict__ nin,
                                                      const float* __restrict__ bias,
                                                      const float* __restrict__ nout,
                                                      const ushort* __restrict__ Wpk,
                                                      ushort* __restrict__ h_next, int n) {
    __shared__ ushort xs[64 * 136];
    const int t = threadIdx.x;
    const int wave = t >> 6, lane = t & 63;
    const int row0 = blockIdx.x * 64;
    const uint* hu = (const uint*)h;
    const float2 bb = *(const float2*)(bias + 2 * lane);

    for (int i = 0; i < 16; ++i) {
        const int lrow = wave * 16 + i;
        const int node = row0 + lrow;
        float a0 = 0.f, a1 = 0.f;
        if (node < n) {
            int beg = row_off[node], end = row_off[node + 1];
            int j = beg;
            for (; j + 7 < end; j += 8) {
                int s0 = csr_src[j],     s1 = csr_src[j + 1];
                int s2 = csr_src[j + 2], s3 = csr_src[j + 3];
                int s4 = csr_src[j + 4], s5 = csr_src[j + 5];
                int s6 = csr_src[j + 6], s7 = csr_src[j + 7];
                uint u0 = hu[(size_t)s0 * 64 + lane];
                uint u1 = hu[(size_t)s1 * 64 + lane];
                uint u2 = hu[(size_t)s2 * 64 + lane];
                uint u3 = hu[(size_t)s3 * 64 + lane];
                uint u4 = hu[(size_t)s4 * 64 + lane];
                uint u5 = hu[(size_t)s5 * 64 + lane];
                uint u6 = hu[(size_t)s6 * 64 + lane];
                uint u7 = hu[(size_t)s7 * 64 + lane];
                a0 += h_lo(u0); a1 += h_hi(u0);
                a0 += h_lo(u1); a1 += h_hi(u1);
                a0 += h_lo(u2); a1 += h_hi(u2);
                a0 += h_lo(u3); a1 += h_hi(u3);
                a0 += h_lo(u4); a1 += h_hi(u4);
                a0 += h_lo(u5); a1 += h_hi(u5);
                a0 += h_lo(u6); a1 += h_hi(u6);
                a0 += h_lo(u7); a1 += h_hi(u7);
            }
            for (; j < end; ++j) {
                uint u = hu[(size_t)csr_src[j] * 64 + lane];
                a0 += h_lo(u); a1 += h_hi(u);
            }
            float nf = nin[node];
            a0 = fmaxf(a0 * nf + bb.x, 0.f);       // relu (layers 1,2 both have relu)
            a1 = fmaxf(a1 * nf + bb.y, 0.f);
            float no = nout[node];
            a0 *= no; a1 *= no;
        }
        ((uint*)xs)[lrow * 68 + lane] = (uint)f2h(a0) | ((uint)f2h(a1) << 16);
    }
    __syncthreads();

    const int r = lane & 15, g = lane >> 4;
    const int nrow0 = row0 + wave * 16;

    half8 a[4];
    #pragma unroll
    for (int kk = 0; kk < 4; ++kk)
        a[kk] = *(const half8*)(&xs[(wave * 16 + r) * 136 + kk * 32 + g * 8]);

    const half8* wp = (const half8*)Wpk;
    #pragma unroll
    for (int ct = 0; ct < OUTN / 16; ++ct) {
        floatx4 acc = {0.f, 0.f, 0.f, 0.f};
        #pragma unroll
        for (int kk = 0; kk < 4; ++kk) {
            half8 b = wp[(ct * 4 + kk) * 64 + lane];
            acc = __builtin_amdgcn_mfma_f32_16x16x32_f16(a[kk], b, acc, 0, 0, 0);
        }
        int col = ct * 16 + r;
        #pragma unroll
        for (int rr = 0; rr < 4; ++rr) {
            int grow = nrow0 + g * 4 + rr;
            if (grow < n) h_next[(size_t)grow * OUTN + col] = f2h(acc[rr]);
        }
    }
}

// ====== CSR aggregation, 64-wide fp16 in, fp32 out (final layer), unroll-4/half ======
__global__ __launch_bounds__(256) void agg64_final(const ushort* __restrict__ h,
                                                   const int* __restrict__ row_off,
                                                   const int* __restrict__ csr_src,
                                                   const float* __restrict__ nin,
                                                   const float* __restrict__ bias,
                                                   float* __restrict__ out, int n) {
    const int wave = threadIdx.x >> 6;
    const int lane = threadIdx.x & 63;
    const int half = lane >> 5, u5 = lane & 31;
    const uint* hu = (const uint*)h;
    for (int node = blockIdx.x * 4 + wave; node < n; node += gridDim.x * 4) {
        int beg = row_off[node], end = row_off[node + 1];
        float a0 = 0.f, a1 = 0.f;
        int j = beg + half;
        for (; j + 6 < end; j += 8) {   // this half handles j, j+2, j+4, j+6
            int sA = csr_src[j],     sB = csr_src[j + 2];
            int sC = csr_src[j + 4], sD = csr_src[j + 6];
            uint uA = hu[(size_t)sA * 32 + u5];
            uint uB = hu[(size_t)sB * 32 + u5];
            uint uC = hu[(size_t)sC * 32 + u5];
            uint uD = hu[(size_t)sD * 32 + u5];
            a0 += h_lo(uA); a1 += h_hi(uA);
            a0 += h_lo(uB); a1 += h_hi(uB);
            a0 += h_lo(uC); a1 += h_hi(uC);
            a0 += h_lo(uD); a1 += h_hi(uD);
        }
        for (; j < end; j += 2) {
            uint u = hu[(size_t)csr_src[j] * 32 + u5];
            a0 += h_lo(u); a1 += h_hi(u);
        }
        float o0 = a0 + __shfl(a0, u5 + 32);
        float o1 = a1 + __shfl(a1, u5 + 32);
        if (lane < 32) {
            float nf = nin[node];
            float2 bb = *(const float2*)(bias + 2 * u5);
            float2 r;
            r.x = o0 * nf + bb.x;
            r.y = o1 * nf + bb.y;
            *(float2*)(out + (size_t)node * 64 + 2 * u5) = r;
        }
    }
}

extern "C" void kernel_launch(void* const* d_in, const int* in_sizes, int n_in,
                              void* d_out, int out_size, void* d_ws, size_t ws_size,
                              hipStream_t stream) {
    const float* in_feat = (const float*)d_in[0];
    const int*   src     = (const int*)d_in[1];
    const int*   dst     = (const int*)d_in[2];
    const float* W1      = (const float*)d_in[3];
    const float* b1      = (const float*)d_in[4];
    const float* W2      = (const float*)d_in[5];
    const float* b2      = (const float*)d_in[6];
    const float* W3      = (const float*)d_in[7];
    const float* b3      = (const float*)d_in[8];

    const int n = in_sizes[0] / 128;
    const int E = in_sizes[1];
    float* out = (float*)d_out;

    // ws: norm_out[n], norm_in[n] (f32); row_off[n+4]; csr_src[E]; Wpk1/2/3; bufA, bufB (ushort)
    float* ws       = (float*)d_ws;
    float* norm_out = ws;
    float* norm_in  = ws + n;
    int*   row_off  = (int*)(ws + 2 * (size_t)n);
    int*   csr_src  = row_off + (n + 4);
    ushort* Wpk1    = (ushort*)(csr_src + E);
    ushort* Wpk2    = Wpk1 + 128 * 128;
    ushort* Wpk3    = Wpk2 + 128 * 128;
    ushort* bufA    = Wpk3 + 128 * 64;
    ushort* bufB    = bufA + (size_t)n * 128;
    // CSR-build overlays inside bufA (dead before gemm layer 1 writes bufA):
    int*    cnt_in   = (int*)bufA;                      // n
    int*    cnt_out  = cnt_in + n;                      // n
    int*    blk_sums = cnt_out + n;                     // ~128
    ushort* PC       = (ushort*)(blk_sums + 128);       // NR*NC*RSTRIDE ushorts (6.4 MB)
    int*    Bbase    = (int*)(PC + (size_t)NR * NC * RSTRIDE);  // NR*NC*RSTRIDE ints (12.8 MB)

    const int nb = (n + SCAN_BLK - 1) / SCAN_BLK;

    // ---- CSR build (no global atomics on rank path) + norms + W pack: 8 dispatches total ----
    hipMemsetAsync(cnt_out, 0, (size_t)n * sizeof(int), stream);
    hist_phaseA<<<2 * NR * NC + 20, THREADS, 0, stream>>>(src, dst, cnt_out, PC,
                                                          W1, W2, W3, Wpk1, Wpk2, Wpk3, n, E);
    scan_phase1<<<nb, THREADS, 0, stream>>>(PC, cnt_in, blk_sums, n);
    scan_phase2<<<1, 1024, 0, stream>>>(blk_sums, nb);
    scan_phase3<<<nb, THREADS, 0, stream>>>(cnt_in, cnt_out, blk_sums, PC, row_off,
                                            norm_in, norm_out, Bbase, n, E);
    csr_phaseC<<<NR * NC, THREADS, 0, stream>>>(src, dst, Bbase, csr_src, n, E);

    const int tile_grid = (n + 63) / 64;
    const int agg_grid  = 4096;

    // ---- layer 1 GEMM ----
    mfma_gemm<128><<<tile_grid, THREADS, 0, stream>>>(in_feat, Wpk1, norm_out, bufA, n);
    // ---- agg1 + gemm2 fused ----
    fused_agg_gemm<128><<<tile_grid, THREADS, 0, stream>>>(bufA, row_off, csr_src, norm_in, b1,
                                                           norm_out, Wpk2, bufB, n);
    // ---- agg2 + gemm3 fused ----
    fused_agg_gemm<64><<<tile_grid, THREADS, 0, stream>>>(bufB, row_off, csr_src, norm_in, b2,
                                                          norm_out, Wpk3, bufA, n);
    // ---- final agg (64-wide, fp32 out) ----
    agg64_final<<<agg_grid, THREADS, 0, stream>>>(bufA, row_off, csr_src, norm_in, b3, out, n);
}

// Round 17
// 372.309 us; speedup vs baseline: 1.0233x; 1.0233x over previous
//
#include <hip/hip_runtime.h>

#define THREADS 256
#define SCAN_BLK 1024
#define NR 8            // node ranges (counting sort + hist)
#define NC 32           // edge chunks
#define RSTRIDE 12544   // padded per-range node stride (>= ceil(100000/8))

typedef __attribute__((ext_vector_type(8))) _Float16 half8;
typedef __attribute__((ext_vector_type(4))) float floatx4;

__device__ __forceinline__ ushort f2h(float f) {
    union { _Float16 h; ushort s; } v;
    v.h = (_Float16)f;               // v_cvt_f16_f32, RNE
    return v.s;
}
__device__ __forceinline__ float h_lo(uint u) {
    union { ushort s; _Float16 h; } v; v.s = (ushort)(u & 0xFFFFu); return (float)v.h;
}
__device__ __forceinline__ float h_hi(uint u) {
    union { ushort s; _Float16 h; } v; v.s = (ushort)(u >> 16); return (float)v.h;
}

// ====== FUSED: src out-degree histogram (blocks [0,256)) + counting-sort phase A
//        dst histogram -> PC (blocks [256,512)). Both stream independent arrays. ======
__global__ __launch_bounds__(256) void hist_phaseA(const int* __restrict__ src,
                                                   const int* __restrict__ dst,
                                                   int* __restrict__ cnt_out,
                                                   ushort* __restrict__ PC, int n, int E) {
    __shared__ uint cnt[RSTRIDE];
    const int Rsz = (n + NR - 1) / NR;
    const int per = (E + NC - 1) / NC;

    if (blockIdx.x < NR * NC) {
        // ---- role A: src out-degree histogram ----
        const int range = blockIdx.x % NR;
        const int chunk = blockIdx.x / NR;
        const int lo = range * Rsz;
        const int R  = min(n - lo, Rsz);
        if (R <= 0) return;
        for (int i = threadIdx.x; i < R; i += THREADS) cnt[i] = 0;
        __syncthreads();
        const int c0 = chunk * per;
        const int c1 = min(E, c0 + per);
        int i = c0 + threadIdx.x * 4;
        for (; i + 4 <= c1; i += THREADS * 4) {
            int4 v = *(const int4*)(src + i);
            if ((unsigned)(v.x - lo) < (unsigned)R) atomicAdd(&cnt[v.x - lo], 1u);
            if ((unsigned)(v.y - lo) < (unsigned)R) atomicAdd(&cnt[v.y - lo], 1u);
            if ((unsigned)(v.z - lo) < (unsigned)R) atomicAdd(&cnt[v.z - lo], 1u);
            if ((unsigned)(v.w - lo) < (unsigned)R) atomicAdd(&cnt[v.w - lo], 1u);
        }
        if (i < c1) {
            for (int e = i; e < c1 && e < i + 4; ++e) {
                int s = src[e];
                if ((unsigned)(s - lo) < (unsigned)R) atomicAdd(&cnt[s - lo], 1u);
            }
        }
        __syncthreads();
        for (int k = threadIdx.x; k < R; k += THREADS) {
            uint c = cnt[k];
            if (c) atomicAdd(&cnt_out[lo + k], (int)c);
        }
    } else {
        // ---- role B: dst histogram, packed 2 nodes/uint -> PC ----
        const int b2 = blockIdx.x - NR * NC;
        const int range = b2 % NR;
        const int chunk = b2 / NR;
        const int lo = range * Rsz;
        const int R  = min(n - lo, Rsz);
        if (R <= 0) return;
        const int Rp = (R + 2) >> 1;
        for (int i = threadIdx.x; i < Rp; i += THREADS) cnt[i] = 0;
        __syncthreads();
        const int c0 = chunk * per;
        const int c1 = min(E, c0 + per);
        int i = c0 + threadIdx.x * 4;
        for (; i + 4 <= c1; i += THREADS * 4) {
            int4 v = *(const int4*)(dst + i);
            int kx = v.x - lo, ky = v.y - lo, kz = v.z - lo, kw = v.w - lo;
            if ((unsigned)kx < (unsigned)R) atomicAdd(&cnt[kx >> 1], (kx & 1) ? 65536u : 1u);
            if ((unsigned)ky < (unsigned)R) atomicAdd(&cnt[ky >> 1], (ky & 1) ? 65536u : 1u);
            if ((unsigned)kz < (unsigned)R) atomicAdd(&cnt[kz >> 1], (kz & 1) ? 65536u : 1u);
            if ((unsigned)kw < (unsigned)R) atomicAdd(&cnt[kw >> 1], (kw & 1) ? 65536u : 1u);
        }
        if (i < c1) {
            for (int e = i; e < c1 && e < i + 4; ++e) {
                int k = dst[e] - lo;
                if ((unsigned)k < (unsigned)R) atomicAdd(&cnt[k >> 1], (k & 1) ? 65536u : 1u);
            }
        }
        __syncthreads();
        ushort* pc = PC + (size_t)(range * NC + chunk) * RSTRIDE;
        for (int k = threadIdx.x; k < R; k += THREADS) {
            uint c = cnt[k >> 1];
            pc[k] = (ushort)((k & 1) ? (c >> 16) : (c & 0xFFFFu));
        }
    }
}

// ====== colsum: cnt_in[node] = sum over chunks of PC ======
__global__ void csr_colsum(const ushort* __restrict__ PC, int* __restrict__ cnt_in, int n) {
    int gk = blockIdx.x * blockDim.x + threadIdx.x;
    if (gk >= n) return;
    const int Rsz = (n + NR - 1) / NR;
    int r = gk / Rsz, k = gk - r * Rsz;
    int t = 0;
    #pragma unroll 4
    for (int c = 0; c < NC; ++c)
        t += PC[(size_t)(r * NC + c) * RSTRIDE + k];
    cnt_in[gk] = t;
}

// ====== mkbase: B[r][c][k] = row_off[node] + prefix_{c'<c} PC ======
__global__ void csr_mkbase(const ushort* __restrict__ PC, const int* __restrict__ row_off,
                           int* __restrict__ B, int n) {
    int gk = blockIdx.x * blockDim.x + threadIdx.x;
    if (gk >= n) return;
    const int Rsz = (n + NR - 1) / NR;
    int r = gk / Rsz, k = gk - r * Rsz;
    int base = row_off[gk];
    for (int c = 0; c < NC; ++c) {
        size_t idx = (size_t)(r * NC + c) * RSTRIDE + k;
        B[idx] = base;
        base += PC[idx];
    }
}

// ====== counting-sort phase C: LDS cursors, scatter csr_src (no global atomics) ======
__global__ __launch_bounds__(256) void csr_phaseC(const int* __restrict__ src,
                                                  const int* __restrict__ dst,
                                                  const int* __restrict__ B,
                                                  int* __restrict__ csr_src, int n, int E) {
    __shared__ int cur[RSTRIDE];
    const int range = blockIdx.x % NR;
    const int chunk = blockIdx.x / NR;
    const int Rsz = (n + NR - 1) / NR;
    const int lo  = range * Rsz;
    const int R   = min(n - lo, Rsz);
    if (R <= 0) return;
    const int* b = B + (size_t)(range * NC + chunk) * RSTRIDE;
    for (int i = threadIdx.x; i < R; i += THREADS) cur[i] = b[i];
    __syncthreads();
    const int per = (E + NC - 1) / NC;
    const int c0 = chunk * per;
    const int c1 = min(E, c0 + per);
    int i = c0 + threadIdx.x * 4;
    for (; i + 4 <= c1; i += THREADS * 4) {
        int4 d = *(const int4*)(dst + i);
        int4 s = *(const int4*)(src + i);
        int kx = d.x - lo, ky = d.y - lo, kz = d.z - lo, kw = d.w - lo;
        if ((unsigned)kx < (unsigned)R) csr_src[atomicAdd(&cur[kx], 1)] = s.x;
        if ((unsigned)ky < (unsigned)R) csr_src[atomicAdd(&cur[ky], 1)] = s.y;
        if ((unsigned)kz < (unsigned)R) csr_src[atomicAdd(&cur[kz], 1)] = s.z;
        if ((unsigned)kw < (unsigned)R) csr_src[atomicAdd(&cur[kw], 1)] = s.w;
    }
    if (i < c1) {
        for (int e = i; e < c1 && e < i + 4; ++e) {
            int k = dst[e] - lo;
            if ((unsigned)k < (unsigned)R) csr_src[atomicAdd(&cur[k], 1)] = src[e];
        }
    }
}

// ====== exclusive scan of cnt_in -> row_off; phase3 also emits norm_in AND norm_out ======
__global__ void scan_phase1(const int* __restrict__ cnt, int* __restrict__ blk_sums, int n) {
    int base = blockIdx.x * SCAN_BLK;
    int t = threadIdx.x;
    int sum = 0;
    for (int i = t; i < SCAN_BLK; i += THREADS) {
        int idx = base + i;
        sum += (idx < n) ? cnt[idx] : 0;
    }
    __shared__ int wsum[4];
    for (int off = 32; off > 0; off >>= 1) sum += __shfl_down(sum, off);
    if ((t & 63) == 0) wsum[t >> 6] = sum;
    __syncthreads();
    if (t == 0) blk_sums[blockIdx.x] = wsum[0] + wsum[1] + wsum[2] + wsum[3];
}

__global__ void scan_phase2(int* __restrict__ blk_sums, int nb) {
    __shared__ int s[1024];
    int t = threadIdx.x;
    s[t] = (t < nb) ? blk_sums[t] : 0;
    __syncthreads();
    for (int off = 1; off < 1024; off <<= 1) {
        int v = s[t];
        if (t >= off) v += s[t - off];
        __syncthreads();
        s[t] = v;
        __syncthreads();
    }
    if (t < nb) blk_sums[t] = (t == 0) ? 0 : s[t - 1];
}

__global__ void scan_phase3(const int* __restrict__ cnt, const int* __restrict__ cnt_out,
                            const int* __restrict__ blk_sums,
                            int* __restrict__ row_off, float* __restrict__ norm_in,
                            float* __restrict__ norm_out, int n, int E) {
    __shared__ int ts[THREADS];
    int b = blockIdx.x, t = threadIdx.x;
    int base = b * SCAN_BLK + t * 4;
    int local[4], val[4]; int s = 0;
    #pragma unroll
    for (int k = 0; k < 4; ++k) {
        local[k] = s;
        int idx = base + k;
        int v = (idx < n) ? cnt[idx] : 0;
        val[k] = v;
        s += v;
    }
    ts[t] = s;
    __syncthreads();
    for (int off = 1; off < THREADS; off <<= 1) {
        int v = ts[t];
        if (t >= off) v += ts[t - off];
        __syncthreads();
        ts[t] = v;
        __syncthreads();
    }
    int excl = (t == 0) ? 0 : ts[t - 1];
    int boff = blk_sums[b];
    #pragma unroll
    for (int k = 0; k < 4; ++k) {
        int idx = base + k;
        if (idx < n) {
            row_off[idx] = boff + excl + local[k];
            norm_in[idx]  = rsqrtf((float)max(val[k], 1));
            norm_out[idx] = rsqrtf((float)max(cnt_out[idx], 1));
        }
    }
    if (b == 0 && t == 0) row_off[n] = E;
}

// ====== fused W fragment pre-pack (all 3 weights, one dispatch, fp16) ======
__device__ __forceinline__ void wpack_one(const float* __restrict__ W, ushort* __restrict__ Wpk,
                                          int OUT, int t) {
    int lane = t & 63, kk = (t >> 6) & 3, ct = t >> 8;
    int col = ct * 16 + (lane & 15);
    int k0 = kk * 32 + (lane >> 4) * 8;
    #pragma unroll
    for (int j = 0; j < 8; ++j)
        Wpk[t * 8 + j] = f2h(W[(size_t)(k0 + j) * OUT + col]);
}

__global__ void wpack_all(const float* __restrict__ W1, const float* __restrict__ W2,
                          const float* __restrict__ W3, ushort* __restrict__ Wpk1,
                          ushort* __restrict__ Wpk2, ushort* __restrict__ Wpk3) {
    int t = blockIdx.x * blockDim.x + threadIdx.x;
    if (t < 2048)      wpack_one(W1, Wpk1, 128, t);
    else if (t < 4096) wpack_one(W2, Wpk2, 128, t - 2048);
    else if (t < 5120) wpack_one(W3, Wpk3, 64,  t - 4096);
}

// ====== MFMA GEMM (layer 1): h = fp16((x*norm) @ W), 64 nodes/block ======
template<int OUT>
__global__ __launch_bounds__(256) void mfma_gemm(const float* __restrict__ x,
                                                 const ushort* __restrict__ Wpk,
                                                 const float* __restrict__ norm,
                                                 ushort* __restrict__ h, int n) {
    __shared__ ushort xs[64 * 136];
    const int t = threadIdx.x;
    const int row0 = blockIdx.x * 64;

    #pragma unroll
    for (int i = 0; i < 8; ++i) {
        int e = (i * 256 + t) * 4;
        int row = e >> 7, col = e & 127;
        int gr = min(row0 + row, n - 1);
        float nf = norm[gr];
        float4 v = *(const float4*)(x + (size_t)gr * 128 + col);
        ushort4 p;
        p.x = f2h(v.x * nf); p.y = f2h(v.y * nf);
        p.z = f2h(v.z * nf); p.w = f2h(v.w * nf);
        *(ushort4*)(&xs[row * 136 + col]) = p;
    }
    __syncthreads();

    const int wave = t >> 6, lane = t & 63;
    const int r = lane & 15, g = lane >> 4;
    const int nrow0 = row0 + wave * 16;

    half8 a[4];
    #pragma unroll
    for (int kk = 0; kk < 4; ++kk)
        a[kk] = *(const half8*)(&xs[(wave * 16 + r) * 136 + kk * 32 + g * 8]);

    const half8* wp = (const half8*)Wpk;
    #pragma unroll
    for (int ct = 0; ct < OUT / 16; ++ct) {
        floatx4 acc = {0.f, 0.f, 0.f, 0.f};
        #pragma unroll
        for (int kk = 0; kk < 4; ++kk) {
            half8 b = wp[(ct * 4 + kk) * 64 + lane];
            acc = __builtin_amdgcn_mfma_f32_16x16x32_f16(a[kk], b, acc, 0, 0, 0);
        }
        int col = ct * 16 + r;
        #pragma unroll
        for (int rr = 0; rr < 4; ++rr) {
            int grow = nrow0 + g * 4 + rr;
            if (grow < n) h[(size_t)grow * OUT + col] = f2h(acc[rr]);
        }
    }
}

// ====== FUSED: agg (128-wide fp16, unroll-8) + finalize + next-layer GEMM ======
template<int OUTN>
__global__ __launch_bounds__(256) void fused_agg_gemm(const ushort* __restrict__ h,
                                                      const int* __restrict__ row_off,
                                                      const int* __restrict__ csr_src,
                                                      const float* __restrict__ nin,
                                                      const float* __restrict__ bias,
                                                      const float* __restrict__ nout,
                                                      const ushort* __restrict__ Wpk,
                                                      ushort* __restrict__ h_next, int n) {
    __shared__ ushort xs[64 * 136];
    const int t = threadIdx.x;
    const int wave = t >> 6, lane = t & 63;
    const int row0 = blockIdx.x * 64;
    const uint* hu = (const uint*)h;
    const float2 bb = *(const float2*)(bias + 2 * lane);

    for (int i = 0; i < 16; ++i) {
        const int lrow = wave * 16 + i;
        const int node = row0 + lrow;
        float a0 = 0.f, a1 = 0.f;
        if (node < n) {
            int beg = row_off[node], end = row_off[node + 1];
            int j = beg;
            for (; j + 7 < end; j += 8) {
                int s0 = csr_src[j],     s1 = csr_src[j + 1];
                int s2 = csr_src[j + 2], s3 = csr_src[j + 3];
                int s4 = csr_src[j + 4], s5 = csr_src[j + 5];
                int s6 = csr_src[j + 6], s7 = csr_src[j + 7];
                uint u0 = hu[(size_t)s0 * 64 + lane];
                uint u1 = hu[(size_t)s1 * 64 + lane];
                uint u2 = hu[(size_t)s2 * 64 + lane];
                uint u3 = hu[(size_t)s3 * 64 + lane];
                uint u4 = hu[(size_t)s4 * 64 + lane];
                uint u5 = hu[(size_t)s5 * 64 + lane];
                uint u6 = hu[(size_t)s6 * 64 + lane];
                uint u7 = hu[(size_t)s7 * 64 + lane];
                a0 += h_lo(u0); a1 += h_hi(u0);
                a0 += h_lo(u1); a1 += h_hi(u1);
                a0 += h_lo(u2); a1 += h_hi(u2);
                a0 += h_lo(u3); a1 += h_hi(u3);
                a0 += h_lo(u4); a1 += h_hi(u4);
                a0 += h_lo(u5); a1 += h_hi(u5);
                a0 += h_lo(u6); a1 += h_hi(u6);
                a0 += h_lo(u7); a1 += h_hi(u7);
            }
            for (; j < end; ++j) {
                uint u = hu[(size_t)csr_src[j] * 64 + lane];
                a0 += h_lo(u); a1 += h_hi(u);
            }
            float nf = nin[node];
            a0 = fmaxf(a0 * nf + bb.x, 0.f);       // relu (layers 1,2 both have relu)
            a1 = fmaxf(a1 * nf + bb.y, 0.f);
            float no = nout[node];
            a0 *= no; a1 *= no;
        }
        ((uint*)xs)[lrow * 68 + lane] = (uint)f2h(a0) | ((uint)f2h(a1) << 16);
    }
    __syncthreads();

    const int r = lane & 15, g = lane >> 4;
    const int nrow0 = row0 + wave * 16;

    half8 a[4];
    #pragma unroll
    for (int kk = 0; kk < 4; ++kk)
        a[kk] = *(const half8*)(&xs[(wave * 16 + r) * 136 + kk * 32 + g * 8]);

    const half8* wp = (const half8*)Wpk;
    #pragma unroll
    for (int ct = 0; ct < OUTN / 16; ++ct) {
        floatx4 acc = {0.f, 0.f, 0.f, 0.f};
        #pragma unroll
        for (int kk = 0; kk < 4; ++kk) {
            half8 b = wp[(ct * 4 + kk) * 64 + lane];
            acc = __builtin_amdgcn_mfma_f32_16x16x32_f16(a[kk], b, acc, 0, 0, 0);
        }
        int col = ct * 16 + r;
        #pragma unroll
        for (int rr = 0; rr < 4; ++rr) {
            int grow = nrow0 + g * 4 + rr;
            if (grow < n) h_next[(size_t)grow * OUTN + col] = f2h(acc[rr]);
        }
    }
}

// ====== CSR aggregation, 64-wide fp16 in, fp32 out (final layer), unroll-4/half ======
__global__ __launch_bounds__(256) void agg64_final(const ushort* __restrict__ h,
                                                   const int* __restrict__ row_off,
                                                   const int* __restrict__ csr_src,
                                                   const float* __restrict__ nin,
                                                   const float* __restrict__ bias,
                                                   float* __restrict__ out, int n) {
    const int wave = threadIdx.x >> 6;
    const int lane = threadIdx.x & 63;
    const int half = lane >> 5, u5 = lane & 31;
    const uint* hu = (const uint*)h;
    for (int node = blockIdx.x * 4 + wave; node < n; node += gridDim.x * 4) {
        int beg = row_off[node], end = row_off[node + 1];
        float a0 = 0.f, a1 = 0.f;
        int j = beg + half;
        for (; j + 6 < end; j += 8) {   // this half handles j, j+2, j+4, j+6
            int sA = csr_src[j],     sB = csr_src[j + 2];
            int sC = csr_src[j + 4], sD = csr_src[j + 6];
            uint uA = hu[(size_t)sA * 32 + u5];
            uint uB = hu[(size_t)sB * 32 + u5];
            uint uC = hu[(size_t)sC * 32 + u5];
            uint uD = hu[(size_t)sD * 32 + u5];
            a0 += h_lo(uA); a1 += h_hi(uA);
            a0 += h_lo(uB); a1 += h_hi(uB);
            a0 += h_lo(uC); a1 += h_hi(uC);
            a0 += h_lo(uD); a1 += h_hi(uD);
        }
        for (; j < end; j += 2) {
            uint u = hu[(size_t)csr_src[j] * 32 + u5];
            a0 += h_lo(u); a1 += h_hi(u);
        }
        float o0 = a0 + __shfl(a0, u5 + 32);
        float o1 = a1 + __shfl(a1, u5 + 32);
        if (lane < 32) {
            float nf = nin[node];
            float2 bb = *(const float2*)(bias + 2 * u5);
            float2 r;
            r.x = o0 * nf + bb.x;
            r.y = o1 * nf + bb.y;
            *(float2*)(out + (size_t)node * 64 + 2 * u5) = r;
        }
    }
}

extern "C" void kernel_launch(void* const* d_in, const int* in_sizes, int n_in,
                              void* d_out, int out_size, void* d_ws, size_t ws_size,
                              hipStream_t stream) {
    const float* in_feat = (const float*)d_in[0];
    const int*   src     = (const int*)d_in[1];
    const int*   dst     = (const int*)d_in[2];
    const float* W1      = (const float*)d_in[3];
    const float* b1      = (const float*)d_in[4];
    const float* W2      = (const float*)d_in[5];
    const float* b2      = (const float*)d_in[6];
    const float* W3      = (const float*)d_in[7];
    const float* b3      = (const float*)d_in[8];

    const int n = in_sizes[0] / 128;
    const int E = in_sizes[1];
    float* out = (float*)d_out;

    // ws: norm_out[n], norm_in[n] (f32); row_off[n+4]; csr_src[E]; Wpk1/2/3; bufA, bufB (ushort)
    float* ws       = (float*)d_ws;
    float* norm_out = ws;
    float* norm_in  = ws + n;
    int*   row_off  = (int*)(ws + 2 * (size_t)n);
    int*   csr_src  = row_off + (n + 4);
    ushort* Wpk1    = (ushort*)(csr_src + E);
    ushort* Wpk2    = Wpk1 + 128 * 128;
    ushort* Wpk3    = Wpk2 + 128 * 128;
    ushort* bufA    = Wpk3 + 128 * 64;
    ushort* bufB    = bufA + (size_t)n * 128;
    // CSR-build overlays inside bufA (dead before gemm layer 1 writes bufA):
    int*    cnt_in   = (int*)bufA;                      // n
    int*    cnt_out  = cnt_in + n;                      // n
    int*    blk_sums = cnt_out + n;                     // ~128
    ushort* PC       = (ushort*)(blk_sums + 128);       // NR*NC*RSTRIDE ushorts (6.4 MB)
    int*    Bbase    = (int*)(PC + (size_t)NR * NC * RSTRIDE);  // NR*NC*RSTRIDE ints (12.8 MB)

    const int nb = (n + SCAN_BLK - 1) / SCAN_BLK;

    // ---- CSR build (no global atomics on rank path) + norms + W pack ----
    hipMemsetAsync(cnt_out, 0, (size_t)n * sizeof(int), stream);
    wpack_all<<<20, THREADS, 0, stream>>>(W1, W2, W3, Wpk1, Wpk2, Wpk3);
    hist_phaseA<<<2 * NR * NC, THREADS, 0, stream>>>(src, dst, cnt_out, PC, n, E);
    csr_colsum<<<(n + THREADS - 1) / THREADS, THREADS, 0, stream>>>(PC, cnt_in, n);
    scan_phase1<<<nb, THREADS, 0, stream>>>(cnt_in, blk_sums, n);
    scan_phase2<<<1, 1024, 0, stream>>>(blk_sums, nb);
    scan_phase3<<<nb, THREADS, 0, stream>>>(cnt_in, cnt_out, blk_sums, row_off, norm_in, norm_out, n, E);
    csr_mkbase<<<(n + THREADS - 1) / THREADS, THREADS, 0, stream>>>(PC, row_off, Bbase, n);
    csr_phaseC<<<NR * NC, THREADS, 0, stream>>>(src, dst, Bbase, csr_src, n, E);

    const int tile_grid = (n + 63) / 64;
    const int agg_grid  = 4096;

    // ---- layer 1 GEMM ----
    mfma_gemm<128><<<tile_grid, THREADS, 0, stream>>>(in_feat, Wpk1, norm_out, bufA, n);
    // ---- agg1 + gemm2 fused ----
    fused_agg_gemm<128><<<tile_grid, THREADS, 0, stream>>>(bufA, row_off, csr_src, norm_in, b1,
                                                           norm_out, Wpk2, bufB, n);
    // ---- agg2 + gemm3 fused ----
    fused_agg_gemm<64><<<tile_grid, THREADS, 0, stream>>>(bufB, row_off, csr_src, norm_in, b2,
                                                          norm_out, Wpk3, bufA, n);
    // ---- final agg (64-wide, fp32 out) ----
    agg64_final<<<agg_grid, THREADS, 0, stream>>>(bufA, row_off, csr_src, norm_in, b3, out, n);
}